// Round 5
// baseline (235.528 us; speedup 1.0000x reference)
//
#include <hip/hip_runtime.h>
#include <hip/hip_fp16.h>

#define PENALTY_N 0.1f
#define CP 33344         // nodes per partition (mult of 64); P=3 covers 100,032
#define MAX_BPP 80       // P*MAX_BPP = 240 blocks ~= 1/CU for phase B
#define ABLK 1024        // threads per block, phase-B scatter

// ---------------------------------------------------------------------------
// Phase A: compute per-edge transfer once, store as fp16.
//   t[e] = |traffic[src]-traffic[dst]| * n * w[e]
// This is the ONLY kernel doing random gathers (12.8M lane-gathers, the
// irreducible minimum). Unconditional, 8 independent gathers per vec4-iter,
// 256-thread blocks at full occupancy -> max memory-level parallelism.
// Also zeroes the scalar accumulator out[nN].
// ---------------------------------------------------------------------------
__global__ __launch_bounds__(256, 8) void compute_t_kernel(
    const int* __restrict__ src_idx,
    const int* __restrict__ dst_idx,
    const float* __restrict__ w,
    const float* __restrict__ traffic,
    __half* __restrict__ tbuf,
    float* __restrict__ out_scalar,
    int nE) {
    const int tid = blockIdx.x * blockDim.x + threadIdx.x;
    const int stride = gridDim.x * blockDim.x;
    if (blockIdx.x == 0 && threadIdx.x == 0) *out_scalar = 0.0f;

    const int nvec = nE >> 2;
    const int4* __restrict__ s4p = (const int4*)src_idx;
    const int4* __restrict__ d4p = (const int4*)dst_idx;
    const float4* __restrict__ w4p = (const float4*)w;
    uint2* __restrict__ t2p = (uint2*)tbuf;   // 4 halves = 8 B per vec4 group

    for (int v = tid; v < nvec; v += stride) {
        int4 s = s4p[v];
        int4 d = d4p[v];
        float4 ww = w4p[v];
        // 8 independent gathers, all issued before any use
        float a0 = traffic[s.x], a1 = traffic[s.y];
        float a2 = traffic[s.z], a3 = traffic[s.w];
        float b0 = traffic[d.x], b1 = traffic[d.y];
        float b2 = traffic[d.z], b3 = traffic[d.w];
        float t0 = fabsf(a0 - b0) * (PENALTY_N * ww.x);
        float t1 = fabsf(a1 - b1) * (PENALTY_N * ww.y);
        float t2 = fabsf(a2 - b2) * (PENALTY_N * ww.z);
        float t3 = fabsf(a3 - b3) * (PENALTY_N * ww.w);
        __half2 h01 = __floats2half2_rn(t0, t1);
        __half2 h23 = __floats2half2_rn(t2, t3);
        uint2 pk;
        pk.x = *(unsigned*)&h01;
        pk.y = *(unsigned*)&h23;
        t2p[v] = pk;
    }
    for (int e = (nvec << 2) + tid; e < nE; e += stride) {
        float t = fabsf(traffic[src_idx[e]] - traffic[dst_idx[e]]) *
                  (PENALTY_N * w[e]);
        tbuf[e] = __float2half_rn(t);
    }
}

// ---------------------------------------------------------------------------
// Phase B: partitioned scatter, NO gathers. Streams (src,dst,t) -- L3-hot on
// re-scans -- and does conditional LDS atomics (exec-masked; dump-slot trick
// removed: same-address LDS atomics serialize per-lane, R4 post-mortem).
// Flush = plain float4 stores to private scratch.
// ---------------------------------------------------------------------------
__global__ __launch_bounds__(ABLK, 4) void part_scatter_kernel(
    const int* __restrict__ src_idx,
    const int* __restrict__ dst_idx,
    const __half* __restrict__ tbuf,
    float* __restrict__ scratch,   // [P][Bpp][CP]
    int nE, int nN, int Bpp) {
    __shared__ float hist[CP];

    const int p = blockIdx.x / Bpp;
    const int b = blockIdx.x % Bpp;
    const int lo = p * CP;
    const unsigned csz = (unsigned)min(CP, nN - lo);
    const int tid = threadIdx.x;

    {
        float4* h4 = (float4*)hist;
        for (int i = tid; i < CP / 4; i += ABLK)
            h4[i] = make_float4(0.f, 0.f, 0.f, 0.f);
    }
    __syncthreads();

    const int nvec = nE >> 2;
    const int4* __restrict__ s4p = (const int4*)src_idx;
    const int4* __restrict__ d4p = (const int4*)dst_idx;
    const uint2* __restrict__ t2p = (const uint2*)tbuf;
    const int stride = Bpp * ABLK;

    for (int v = b * ABLK + tid; v < nvec; v += stride) {
        int4 s = s4p[v];
        int4 d = d4p[v];
        uint2 pk = t2p[v];
        __half2 h01 = *(__half2*)&pk.x;
        __half2 h23 = *(__half2*)&pk.y;
        float t0 = __low2float(h01), t1 = __high2float(h01);
        float t2 = __low2float(h23), t3 = __high2float(h23);

        unsigned u;
        u = (unsigned)(s.x - lo); if (u < csz) atomicAdd(&hist[u], -t0);
        u = (unsigned)(d.x - lo); if (u < csz) atomicAdd(&hist[u],  t0);
        u = (unsigned)(s.y - lo); if (u < csz) atomicAdd(&hist[u], -t1);
        u = (unsigned)(d.y - lo); if (u < csz) atomicAdd(&hist[u],  t1);
        u = (unsigned)(s.z - lo); if (u < csz) atomicAdd(&hist[u], -t2);
        u = (unsigned)(d.z - lo); if (u < csz) atomicAdd(&hist[u],  t2);
        u = (unsigned)(s.w - lo); if (u < csz) atomicAdd(&hist[u], -t3);
        u = (unsigned)(d.w - lo); if (u < csz) atomicAdd(&hist[u],  t3);
    }
    for (int e = (nvec << 2) + b * ABLK + tid; e < nE; e += stride) {
        float t = __half2float(tbuf[e]);
        unsigned u;
        u = (unsigned)(src_idx[e] - lo); if (u < csz) atomicAdd(&hist[u], -t);
        u = (unsigned)(dst_idx[e] - lo); if (u < csz) atomicAdd(&hist[u],  t);
    }

    __syncthreads();
    float* dst = scratch + (size_t)blockIdx.x * CP;
    {
        const int n4 = (int)(csz >> 2);
        float4* d4 = (float4*)dst;
        const float4* h4 = (const float4*)hist;
        for (int i = tid; i < n4; i += ABLK) d4[i] = h4[i];
        for (int i = (n4 << 2) + tid; i < (int)csz; i += ABLK) dst[i] = hist[i];
    }
}

// ---------------------------------------------------------------------------
// Phase C: per-node sum of Bpp private copies + base traffic; writes
// new_traffic and fuses the service-efficiency reduction.
// ---------------------------------------------------------------------------
__global__ __launch_bounds__(256) void part_reduce_kernel(
    const float* __restrict__ scratch,
    const float* __restrict__ traffic,
    const float* __restrict__ yield_rate,
    const float* __restrict__ cost,
    float* __restrict__ out,        // [nN] new_traffic, out[nN] scalar
    int nN, int Bpp) {
    const int tid = blockIdx.x * blockDim.x + threadIdx.x;
    const int stride = gridDim.x * blockDim.x;

    float acc = 0.0f;
    for (int i = tid; i < nN; i += stride) {
        int p = i / CP;
        int off = i - p * CP;
        const float* base = scratch + (size_t)p * Bpp * CP + off;

        float s0 = traffic[i], s1 = 0.0f, s2 = 0.0f, s3 = 0.0f;
        int b = 0;
        for (; b + 8 <= Bpp; b += 8) {
            const float* q = base + (size_t)b * CP;
            float a0 = q[0 * (size_t)CP];
            float a1 = q[1 * (size_t)CP];
            float a2 = q[2 * (size_t)CP];
            float a3 = q[3 * (size_t)CP];
            float a4 = q[4 * (size_t)CP];
            float a5 = q[5 * (size_t)CP];
            float a6 = q[6 * (size_t)CP];
            float a7 = q[7 * (size_t)CP];
            s0 += a0 + a4;
            s1 += a1 + a5;
            s2 += a2 + a6;
            s3 += a3 + a7;
        }
        for (; b < Bpp; ++b) s0 += base[(size_t)b * CP];
        float s = (s0 + s1) + (s2 + s3);
        out[i] = s;
        acc = fmaf(yield_rate[i], s, acc) - cost[i];
    }

    #pragma unroll
    for (int off = 32; off > 0; off >>= 1) acc += __shfl_down(acc, off, 64);

    __shared__ float wsum[4];
    const int lane = threadIdx.x & 63;
    const int wid = threadIdx.x >> 6;
    if (lane == 0) wsum[wid] = acc;
    __syncthreads();
    if (threadIdx.x == 0)
        atomicAdd(&out[nN], wsum[0] + wsum[1] + wsum[2] + wsum[3]);
}

// ---------------------------------------------------------------------------
// Fallback path (ws too small): direct-atomic version.
// ---------------------------------------------------------------------------
__global__ void init_out_kernel(const float* __restrict__ traffic,
                                float* __restrict__ out, int nN) {
    int i = blockIdx.x * blockDim.x + threadIdx.x;
    if (i < nN) out[i] = traffic[i];
    else if (i == nN) out[i] = 0.0f;
}

__global__ __launch_bounds__(256) void edge_scatter_kernel(
    const int* __restrict__ src_idx, const int* __restrict__ dst_idx,
    const float* __restrict__ w, const float* __restrict__ traffic,
    float* __restrict__ out, int nE) {
    const int tid = blockIdx.x * blockDim.x + threadIdx.x;
    const int stride = gridDim.x * blockDim.x;
    for (int e = tid; e < nE; e += stride) {
        int s = src_idx[e];
        int d = dst_idx[e];
        float t = fabsf(traffic[s] - traffic[d]) * (PENALTY_N * w[e]);
        atomicAdd(&out[s], -t);
        atomicAdd(&out[d], t);
    }
}

__global__ __launch_bounds__(256) void reduce_kernel(
    const float* __restrict__ new_traffic, const float* __restrict__ yield_rate,
    const float* __restrict__ cost, float* __restrict__ total, int nN) {
    const int tid = blockIdx.x * blockDim.x + threadIdx.x;
    const int stride = gridDim.x * blockDim.x;
    float acc = 0.0f;
    for (int i = tid; i < nN; i += stride)
        acc = fmaf(yield_rate[i], new_traffic[i], acc) - cost[i];
    #pragma unroll
    for (int off = 32; off > 0; off >>= 1) acc += __shfl_down(acc, off, 64);
    __shared__ float wsum[4];
    const int lane = threadIdx.x & 63;
    const int wid = threadIdx.x >> 6;
    if (lane == 0) wsum[wid] = acc;
    __syncthreads();
    if (threadIdx.x == 0)
        atomicAdd(total, wsum[0] + wsum[1] + wsum[2] + wsum[3]);
}

// ---------------------------------------------------------------------------
extern "C" void kernel_launch(void* const* d_in, const int* in_sizes, int n_in,
                              void* d_out, int out_size, void* d_ws, size_t ws_size,
                              hipStream_t stream) {
    const int* edge_index = (const int*)d_in[0];     // (2, E) flat
    const float* edge_weight = (const float*)d_in[1];
    const float* nodes_yield = (const float*)d_in[2];
    const float* nodes_traffic = (const float*)d_in[3];
    const float* nodes_cost = (const float*)d_in[4];
    float* out = (float*)d_out;

    const int nE = in_sizes[1];
    const int nN = in_sizes[2];
    const int* src_idx = edge_index;
    const int* dst_idx = edge_index + nE;

    const int P = (nN + CP - 1) / CP;   // 3 for nN=100K

    // ws layout: [ t (fp16, nE, 256B-aligned) | scratch (P*Bpp*CP floats) ]
    size_t tbytes = (((size_t)nE * sizeof(__half)) + 255) & ~(size_t)255;
    size_t rem = (ws_size > tbytes) ? (ws_size - tbytes) : 0;
    int Bpp = (int)(rem / ((size_t)P * CP * sizeof(float)));
    if (Bpp > MAX_BPP) Bpp = MAX_BPP;

    if (Bpp >= 16 && P <= 8) {
        __half* tbuf = (__half*)d_ws;
        float* scratch = (float*)((char*)d_ws + tbytes);

        compute_t_kernel<<<2048, 256, 0, stream>>>(
            src_idx, dst_idx, edge_weight, nodes_traffic,
            tbuf, out + nN, nE);
        part_scatter_kernel<<<P * Bpp, ABLK, 0, stream>>>(
            src_idx, dst_idx, tbuf, scratch, nE, nN, Bpp);
        int rgrid = (nN + 255) / 256;
        part_reduce_kernel<<<rgrid, 256, 0, stream>>>(
            scratch, nodes_traffic, nodes_yield, nodes_cost, out, nN, Bpp);
    } else {
        int grid = (nN + 1 + 255) / 256;
        init_out_kernel<<<grid, 256, 0, stream>>>(nodes_traffic, out, nN);
        edge_scatter_kernel<<<2048, 256, 0, stream>>>(src_idx, dst_idx,
                                                      edge_weight, nodes_traffic,
                                                      out, nE);
        reduce_kernel<<<256, 256, 0, stream>>>(out, nodes_yield, nodes_cost,
                                               out + nN, nN);
    }
}